// Round 6
// baseline (828.598 us; speedup 1.0000x reference)
//
#include <hip/hip_runtime.h>

// TopK-and-scatter: out[r,c] = x[r,c] if x[r,c] is among the top-64 of row r
// (ties at threshold broken by LOWEST column index, matching lax.top_k), else 0.
// R6: software-pipelined rows. Each block handles RPB consecutive rows; raw
// loads for row i+1 are issued before select/write of row i, and all fast-path
// barriers are raw s_barrier + lgkmcnt(0) only (no vmcnt drain), so the next
// row's HBM loads stay in flight through the entire select+write of row i.
// Select: positive-only 12-bit histogram (bits [30:19]) -> crossing bin ->
// candidate list -> per-thread exact composite rank (key desc, col asc).
// Exact bitwise-search slow path (block-uniform) for pathological inputs.

typedef float f32x4 __attribute__((ext_vector_type(4)));
typedef unsigned int u32;
typedef u32 u32x4 __attribute__((ext_vector_type(4)));

#define TPB   1024
#define COLS  32768
#define EPT   32
#define KSEL  64u
#define CAP   2048u
#define RPB   16

// LDS-only barrier: orders LDS ops across the block WITHOUT draining vmcnt,
// so in-flight global loads survive. (8-phase GEMM template pattern, m201.)
__device__ __forceinline__ void ldsBarrier() {
    asm volatile("s_waitcnt lgkmcnt(0)" ::: "memory");
    __builtin_amdgcn_s_barrier();
    asm volatile("" ::: "memory");
}

__device__ __forceinline__ u32 blockSum(u32 v, u32* wtot, int lane, int wid)
{
    #pragma unroll
    for (int off = 32; off >= 1; off >>= 1) v += __shfl_down(v, off);
    if (lane == 0) wtot[wid] = v;
    __syncthreads();
    u32 t = 0;
    #pragma unroll
    for (int w = 0; w < 16; ++w) t += wtot[w];
    __syncthreads();
    return t;
}

__global__ __launch_bounds__(TPB) void topk_scatter_kernel(
    const float* __restrict__ x, float* __restrict__ out, int totalRows)
{
    __shared__ u32 hist[4096];
    __shared__ u32 wtot[16];
    __shared__ int sBin;
    __shared__ u32 sAbove;
    __shared__ u32 candN;
    __shared__ u32 candKey[CAP];
    __shared__ u32 candCol[CAP];

    const int tid  = threadIdx.x;
    const int lane = tid & 63;
    const int wid  = tid >> 6;
    const int r0   = blockIdx.x * RPB;
    if (r0 >= totalRows) return;

    // ---- prologue: zero hist, issue row r0 loads ----
    ((u32x4*)hist)[tid] = (u32x4)(0u);
    if (tid == 0) { sBin = -1; candN = 0u; }
    f32x4 raw[8];
    {
        const f32x4* __restrict__ xr = (const f32x4*)(x + (long long)r0 * COLS);
        #pragma unroll
        for (int j = 0; j < 8; ++j) raw[j] = xr[j * TPB + tid];
    }
    ldsBarrier();                                      // zeros visible; loads fly

    #pragma unroll 1
    for (int i = 0; i < RPB; ++i) {
        const int row = r0 + i;
        if (row >= totalRows) break;                   // block-uniform

        // ---- convert raw -> keys (compiler emits counted vmcnt wait) ----
        u32 key[EPT];
        #pragma unroll
        for (int j = 0; j < 8; ++j) {
            #pragma unroll
            for (int l = 0; l < 4; ++l) {
                const u32 b = __float_as_uint(raw[j][l]);
                key[j * 4 + l] = b ^ ((u32)((int)b >> 31) | 0x80000000u);
            }
        }

        // ---- issue NEXT row's loads (no use until next iteration) ----
        if (i + 1 < RPB && row + 1 < totalRows) {
            const f32x4* __restrict__ xn =
                (const f32x4*)(x + (long long)(row + 1) * COLS);
            #pragma unroll
            for (int j = 0; j < 8; ++j) raw[j] = xn[j * TPB + tid];
        }

        if (tid == 0) { sBin = -1; candN = 0u; }       // safe: >=3 barriers from readers

        // ---- positive-only histogram: bins = bits [30:19] ----
        #pragma unroll
        for (int e = 0; e < EPT; ++e) {
            const u32 k = key[e];
            if (k & 0x80000000u) atomicAdd(&hist[(k & 0x7fffffffu) >> 19], 1u);
        }
        ldsBarrier();                                  // B2: hist complete

        // ---- suffix scan; thread owns bins [4*tid,4*tid+4); zero after read ----
        u32 need = KSEL;
        {
            const u32x4 h = ((const u32x4*)hist)[tid];
            ((u32x4*)hist)[tid] = (u32x4)(0u);         // ready for next row
            const u32 ls3 = h[3];
            const u32 ls2 = h[2] + ls3;
            const u32 ls1 = h[1] + ls2;
            const u32 ls0 = h[0] + ls1;
            u32 v = ls0;
            #pragma unroll
            for (int off = 1; off < 64; off <<= 1) {
                const u32 t = __shfl_down(v, off);
                if (lane + off < 64) v += t;
            }
            if (lane == 0) wtot[wid] = v;
            ldsBarrier();                              // B3: wtot ready
            u32 tailWaves = 0u;
            for (int w = wid + 1; w < 16; ++w) tailWaves += wtot[w];
            const u32 thrTail = tailWaves + (v - ls0);
            const u32 S0 = ls0 + thrTail, S1 = ls1 + thrTail, S2 = ls2 + thrTail,
                      S3 = ls3 + thrTail, S4 = thrTail;
            if (S0 >= need && S1 < need) { sBin = 4 * tid + 0; sAbove = S1; }
            if (S1 >= need && S2 < need) { sBin = 4 * tid + 1; sAbove = S2; }
            if (S2 >= need && S3 < need) { sBin = 4 * tid + 2; sAbove = S3; }
            if (S3 >= need && S4 < need) { sBin = 4 * tid + 3; sAbove = S4; }
            ldsBarrier();                              // B4: crossing known
        }
        const int b1s = sBin;                          // snapshot immediately
        const u32 above = sAbove;
        bool fast = (b1s >= 0);
        u32 b1 = 0, C = 0;

        if (fast) {
            b1 = (u32)b1s;
            need = KSEL - above;                       // 1 <= need <= count(b1)
            // ---- collect crossing-bin candidates ----
            #pragma unroll
            for (int e = 0; e < EPT; ++e) {
                const u32 k = key[e];
                if ((k & 0x80000000u) && ((k & 0x7fffffffu) >> 19) == b1) {
                    const u32 p = atomicAdd(&candN, 1u);
                    if (p < CAP) {
                        candKey[p] = k;
                        candCol[p] = (u32)(((e >> 2) * TPB + tid) * 4 + (e & 3));
                    }
                }
            }
            ldsBarrier();                              // B5: candidates ready
            C = candN;                                 // snapshot immediately
            fast = (C <= CAP);
        }

        f32x4* __restrict__ orow = (f32x4*)(out + (long long)row * COLS);

        if (fast) {
            // ---- fused write: per-thread exact rank for own b1 elements ----
            #pragma unroll
            for (int j = 0; j < 8; ++j) {
                f32x4 o;
                #pragma unroll
                for (int l = 0; l < 4; ++l) {
                    const u32 k = key[j * 4 + l];
                    bool sel = false;
                    if (k & 0x80000000u) {
                        const u32 kb = (k & 0x7fffffffu) >> 19;
                        if (kb > b1) sel = true;
                        else if (kb == b1) {
                            const u32 col = (u32)((j * TPB + tid) * 4 + l);
                            u32 r = 0;
                            for (u32 q = 0; q < C; ++q) {   // LDS broadcast
                                const u32 kq = candKey[q];
                                r += (kq > k || (kq == k && candCol[q] < col))
                                         ? 1u : 0u;
                            }
                            sel = (r < need);
                        }
                    }
                    o[l] = sel ? __uint_as_float(k ^ 0x80000000u) : 0.0f;
                }
                orow[j * TPB + tid] = o;
            }
        } else {
            // ---- exact slow path (any input): bitwise searches ----
            u32 pfx = 0u;
            for (int bit = 31; bit >= 0; --bit) {
                const u32 trial = pfx | (1u << bit);
                u32 loc = 0u;
                #pragma unroll
                for (int e = 0; e < EPT; ++e) loc += (key[e] >= trial) ? 1u : 0u;
                if (blockSum(loc, wtot, lane, wid) >= KSEL) pfx = trial;
            }
            const u32 T = pfx;                         // 64th largest key
            u32 loc = 0u;
            #pragma unroll
            for (int e = 0; e < EPT; ++e) loc += (key[e] > T) ? 1u : 0u;
            const u32 needEq = KSEL - blockSum(loc, wtot, lane, wid);
            u32 cv = 0u;
            for (int bit = 14; bit >= 0; --bit) {
                const u32 trial = cv | (1u << bit);
                u32 l2 = 0u;
                #pragma unroll
                for (int e = 0; e < EPT; ++e) {
                    const u32 col = (u32)(((e >> 2) * TPB + tid) * 4 + (e & 3));
                    l2 += (key[e] == T && col < trial) ? 1u : 0u;
                }
                if (blockSum(l2, wtot, lane, wid) < needEq) cv = trial;
            }
            const u32 colT = cv;
            #pragma unroll
            for (int j = 0; j < 8; ++j) {
                f32x4 o;
                #pragma unroll
                for (int l = 0; l < 4; ++l) {
                    const u32 k = key[j * 4 + l];
                    const u32 col = (u32)((j * TPB + tid) * 4 + l);
                    const bool sel = (k > T) || (k == T && col <= colT);
                    const float val =
                        __uint_as_float((k & 0x80000000u) ? (k ^ 0x80000000u) : ~k);
                    o[l] = sel ? val : 0.0f;
                }
                orow[j * TPB + tid] = o;
            }
            // re-zero hist contract for next iteration is unaffected (slow path
            // never wrote hist), wtot rewritten each scan.
        }
    }
}

extern "C" void kernel_launch(void* const* d_in, const int* in_sizes, int n_in,
                              void* d_out, int out_size, void* d_ws, size_t ws_size,
                              hipStream_t stream)
{
    (void)n_in; (void)out_size; (void)d_ws; (void)ws_size;
    const float* x = (const float*)d_in[0];
    float* out = (float*)d_out;
    const int rows = in_sizes[0] / COLS;
    const int grid = (rows + RPB - 1) / RPB;
    topk_scatter_kernel<<<dim3(grid), dim3(TPB), 0, stream>>>(x, out, rows);
}